// Round 4
// baseline (142.624 us; speedup 1.0000x reference)
//
#include <hip/hip_runtime.h>
#include <hip/hip_bf16.h>

// FastCapsNetMulti via bf16 MFMA, fused:
//  k1 prep_w: wh -> wtb[9][32][160] bf16
//  k2 conv_both: blocks 0..511  = HSI conv (LDS-staged bf16, 9-tap shifted MFMA GEMM)
//                blocks 512..575 = SAR conv (fp32 VALU, uniform scalar weights)
//                both -> squash -> capsb[n][b][8] bf16  (routing A-layout)
//  k3 routing: s[b,cj] = sum caps*W  (M64 x N160 x K65536 MFMA, k-split 128)
//  k4 finalize: reduce + squash + |v|
// B=64, H=W=32, N=8192, classes=10, class_dim=16, cap_dim=8.

typedef __attribute__((ext_vector_type(8))) short bf16x8s;
typedef __attribute__((ext_vector_type(4))) float f32x4;

__device__ inline short f2bf(float f) {
    __hip_bfloat16 h = __float2bfloat16(f);
    return *reinterpret_cast<short*>(&h);
}

// ---------------- prep: wh[32][144][9] -> wtb[9][32][160] bf16 (zero-pad cin) --
__global__ __launch_bounds__(256) void prep_w_kernel(const float* __restrict__ wh,
                                                     short* __restrict__ wtb) {
    int idx = blockIdx.x * 256 + threadIdx.x;   // < 9*32*160 = 46080
    if (idx >= 46080) return;
    int tap = idx / 5120;
    int rest = idx - tap * 5120;
    int oc = rest / 160;
    int cin = rest - oc * 160;
    short v = 0;
    if (cin < 144) v = f2bf(wh[(oc * 144 + cin) * 9 + tap]);
    wtb[idx] = v;
}

// ---------------- fused conv (HSI MFMA + SAR VALU) ---------------------------
// HSI: grid blocks 0..511 = b(64) x ytile(8, 4 rows each). 256 thr = 4 waves,
// wave = one output row. LDS xs[6 rows][32 x][168 ch-pad] bf16, staged from
// global fp32. K = 9 taps x 160. C-tile via LDS -> squash -> capsb.
// SAR: blocks 512..575 = b. Thread = 4 pixels, all 32 oc, weights uniform.
__global__ __launch_bounds__(256) void conv_both_kernel(
        const float* __restrict__ x_hsi, const short* __restrict__ wtb,
        const float* __restrict__ bh,
        const float* __restrict__ x_sar, const float* __restrict__ wsar,
        const float* __restrict__ bs,
        short* __restrict__ capsb) {
    __shared__ union {
        short xs[6][32][168];   // 64512 B
        float ct[128][33];      // 16896 B
    } sm;
    int t = threadIdx.x;

    if (blockIdx.x < 512) {
        int b = blockIdx.x >> 3;
        int y0 = (blockIdx.x & 7) << 2;

        // ---- stage rows y0-1..y0+4 (6 rows), ch 0..143 -> bf16 LDS ----------
        {
            int x = t & 31;
            int i0 = t >> 5;   // 0..7
            const float* xb_ = x_hsi + (size_t)b * 144 * 1024;
            for (int item = i0; item < 432; item += 8) {   // 6 rows * 72 ch-pairs
                int row = item / 72;
                int cp = item - row * 72;
                int iy = y0 - 1 + row;
                unsigned u = 0;
                if ((unsigned)iy < 32u) {
                    float f0 = xb_[(size_t)(2 * cp) * 1024 + iy * 32 + x];
                    float f1 = xb_[(size_t)(2 * cp + 1) * 1024 + iy * 32 + x];
                    u = (unsigned)(unsigned short)f2bf(f0)
                      | ((unsigned)(unsigned short)f2bf(f1) << 16);
                }
                *(unsigned*)&sm.xs[row][x][2 * cp] = u;
            }
            for (int item = i0; item < 48; item += 8) {    // zero ch 144..159
                int row = item >> 3;
                int c4 = item & 7;
                *(unsigned*)&sm.xs[row][x][144 + 2 * c4] = 0;
            }
        }
        __syncthreads();

        // ---- MFMA: wave wv = output row y0+wv; 2 x-halves x 2 oc-tiles ------
        int l = t & 63;
        int wv = t >> 6;
        int l15 = l & 15, lhi = l >> 4;
        int kofs = lhi * 8;

        f32x4 acc[2][2] = {{{0.f,0.f,0.f,0.f},{0.f,0.f,0.f,0.f}},
                           {{0.f,0.f,0.f,0.f},{0.f,0.f,0.f,0.f}}};
        const bf16x8s zf = {0,0,0,0,0,0,0,0};

        #pragma unroll
        for (int tap = 0; tap < 9; ++tap) {
            int dy = tap / 3, dx = tap % 3;
            int lrow = wv + dy;                 // 0..5 into xs
            int ix0 = l15 + dx - 1;
            int ix1 = 16 + l15 + dx - 1;
            bool ok0 = (unsigned)ix0 < 32u;
            bool ok1 = (unsigned)ix1 < 32u;
            int ix0c = ok0 ? ix0 : 0;
            int ix1c = ok1 ? ix1 : 0;
            const short* xa0 = &sm.xs[lrow][ix0c][kofs];
            const short* xa1 = &sm.xs[lrow][ix1c][kofs];
            const short* wa = wtb + ((size_t)tap * 32 + l15) * 160 + kofs;
            #pragma unroll
            for (int kc = 0; kc < 5; ++kc) {
                bf16x8s a0 = *(const bf16x8s*)(xa0 + kc * 32);
                bf16x8s a1 = *(const bf16x8s*)(xa1 + kc * 32);
                a0 = ok0 ? a0 : zf;
                a1 = ok1 ? a1 : zf;
                bf16x8s b0 = *(const bf16x8s*)(wa + kc * 32);
                bf16x8s b1 = *(const bf16x8s*)(wa + 16 * 160 + kc * 32);
                acc[0][0] = __builtin_amdgcn_mfma_f32_16x16x32_bf16(a0, b0, acc[0][0], 0, 0, 0);
                acc[0][1] = __builtin_amdgcn_mfma_f32_16x16x32_bf16(a0, b1, acc[0][1], 0, 0, 0);
                acc[1][0] = __builtin_amdgcn_mfma_f32_16x16x32_bf16(a1, b0, acc[1][0], 0, 0, 0);
                acc[1][1] = __builtin_amdgcn_mfma_f32_16x16x32_bf16(a1, b1, acc[1][1], 0, 0, 0);
            }
        }
        __syncthreads();   // xs reads done in all waves before ct overwrites

        // C row-in-tile = lhi*4+r = x within half; col = l15 = oc within tile
        #pragma unroll
        for (int xh = 0; xh < 2; ++xh)
            #pragma unroll
            for (int nt = 0; nt < 2; ++nt)
                #pragma unroll
                for (int r = 0; r < 4; ++r)
                    sm.ct[wv * 32 + xh * 16 + lhi * 4 + r][nt * 16 + l15] = acc[xh][nt][r];
        __syncthreads();

        // ---- epilogue: 512 capsules, thread handles q = t, t+256 ------------
        #pragma unroll
        for (int h = 0; h < 2; ++h) {
            int q = t + h * 256;
            int p = q >> 2;          // local pixel 0..127
            int cap = q & 3;
            float s[8];
            float sq = 0.0f;
            #pragma unroll
            for (int d = 0; d < 8; ++d) {
                s[d] = sm.ct[p][cap * 8 + d] + bh[cap * 8 + d];
                sq += s[d] * s[d];
            }
            float scale = sq / ((1.0f + sq) * sqrtf(sq + 1e-8f));
            int pix = (y0 + (p >> 5)) * 32 + (p & 31);
            int n = pix * 4 + cap;
            bf16x8s o;
            #pragma unroll
            for (int d = 0; d < 8; ++d) o[d] = f2bf(s[d] * scale);
            *(bf16x8s*)(capsb + ((size_t)n * 64 + b) * 8) = o;
        }
    } else {
        // ------------------------- SAR conv ----------------------------------
        int b = blockIdx.x - 512;
        const float* xb_ = x_sar + (size_t)b * 4 * 1024;
        for (int i = 0; i < 4; ++i) {
            int px = t + i * 256;
            int y = px >> 5, x = px & 31;
            float acc[32];
            #pragma unroll
            for (int oc = 0; oc < 32; ++oc) acc[oc] = bs[oc];
            #pragma unroll
            for (int tap = 0; tap < 9; ++tap) {
                int dy = tap / 3, dx = tap % 3;
                int iy = y + dy - 1, ix = x + dx - 1;
                bool ok = ((unsigned)iy < 32u) && ((unsigned)ix < 32u);
                int off = ok ? (iy * 32 + ix) : 0;
                float v[4];
                #pragma unroll
                for (int ch = 0; ch < 4; ++ch) {
                    float ld = xb_[(size_t)ch * 1024 + off];
                    v[ch] = ok ? ld : 0.0f;
                }
                #pragma unroll
                for (int oc = 0; oc < 32; ++oc)
                    #pragma unroll
                    for (int ch = 0; ch < 4; ++ch)
                        acc[oc] += v[ch] * wsar[(oc * 4 + ch) * 9 + tap];
            }
            #pragma unroll
            for (int cap = 0; cap < 4; ++cap) {
                float sq = 0.0f;
                #pragma unroll
                for (int d = 0; d < 8; ++d) sq += acc[cap * 8 + d] * acc[cap * 8 + d];
                float scale = sq / ((1.0f + sq) * sqrtf(sq + 1e-8f));
                int n = 4096 + px * 4 + cap;
                bf16x8s o;
                #pragma unroll
                for (int d = 0; d < 8; ++d) o[d] = f2bf(acc[cap * 8 + d] * scale);
                *(bf16x8s*)(capsb + ((size_t)n * 64 + b) * 8) = o;
            }
        }
    }
}

// ---------------- routing via MFMA -------------------------------------------
// grid (kc 128) x (ntile 10). 4 waves, wave = 4 k-steps (16 n). A = capsb[n][b][8]
// (contiguous 256B per 16-lane group); B = W fp32 -> bf16 inline.
__global__ __launch_bounds__(256) void routing_mfma_kernel(
        const short* __restrict__ capsb, const float* __restrict__ W,
        float* __restrict__ partials) {
    __shared__ float red[4][64][18];
    int t = threadIdx.x;
    int l = t & 63;
    int wv = t >> 6;
    int l15 = l & 15, lhi = l >> 4;
    int kc = blockIdx.x;
    int ntile = blockIdx.y;
    int cj = ntile * 16 + l15;

    f32x4 acc[4] = {{0.f,0.f,0.f,0.f},{0.f,0.f,0.f,0.f},{0.f,0.f,0.f,0.f},{0.f,0.f,0.f,0.f}};

    int kk0 = kc * 16 + wv * 4;          // 4-n group units
    #pragma unroll
    for (int ks = 0; ks < 4; ++ks) {
        int n = (kk0 + ks) * 4 + lhi;
        const float* wp = W + ((size_t)n * 160 + cj) * 8;
        float4 w0 = *(const float4*)wp;
        float4 w1 = *(const float4*)(wp + 4);
        union { short s[8]; bf16x8s v; } bu;
        bu.s[0] = f2bf(w0.x); bu.s[1] = f2bf(w0.y);
        bu.s[2] = f2bf(w0.z); bu.s[3] = f2bf(w0.w);
        bu.s[4] = f2bf(w1.x); bu.s[5] = f2bf(w1.y);
        bu.s[6] = f2bf(w1.z); bu.s[7] = f2bf(w1.w);
        const short* ap = capsb + (size_t)n * 512;   // [n][b 64][8]
        #pragma unroll
        for (int mt = 0; mt < 4; ++mt) {
            bf16x8s afrag = *(const bf16x8s*)(ap + (mt * 16 + l15) * 8);
            acc[mt] = __builtin_amdgcn_mfma_f32_16x16x32_bf16(afrag, bu.v, acc[mt], 0, 0, 0);
        }
    }

    #pragma unroll
    for (int mt = 0; mt < 4; ++mt)
        #pragma unroll
        for (int r = 0; r < 4; ++r)
            red[wv][mt * 16 + lhi * 4 + r][l15] = acc[mt][r];
    __syncthreads();

    for (int idx = t; idx < 1024; idx += 256) {
        int b = idx >> 4, cjl = idx & 15;
        float sum = red[0][b][cjl] + red[1][b][cjl] + red[2][b][cjl] + red[3][b][cjl];
        partials[(((size_t)kc * 10 + ntile) * 64 + b) * 16 + cjl] = sum;
    }
}

// ---------------- final reduce + squash + norm -------------------------------
__global__ __launch_bounds__(256) void finalize_kernel(
        const float* __restrict__ partials, float* __restrict__ out) {
    __shared__ float s_sh[160];
    int t = threadIdx.x;
    int b = blockIdx.x;
    if (t < 160) {
        int nt = t >> 4, cjl = t & 15;
        float s = 0.0f;
        #pragma unroll 8
        for (int kc = 0; kc < 128; ++kc)
            s += partials[(((size_t)kc * 10 + nt) * 64 + b) * 16 + cjl];
        s_sh[t] = s * (1.0f / 8192.0f);
    }
    __syncthreads();
    if (t < 10) {
        float sq = 0.0f;
        #pragma unroll
        for (int j = 0; j < 16; ++j) {
            float v = s_sh[t * 16 + j];
            sq += v * v;
        }
        float scale = sq / ((1.0f + sq) * sqrtf(sq + 1e-8f));
        out[b * 10 + t] = sqrtf(sq) * scale;
    }
}

extern "C" void kernel_launch(void* const* d_in, const int* in_sizes, int n_in,
                              void* d_out, int out_size, void* d_ws, size_t ws_size,
                              hipStream_t stream) {
    const float* x_hsi = (const float*)d_in[0];   // [64,144,32,32]
    const float* x_sar = (const float*)d_in[1];   // [64,4,32,32]
    const float* wh    = (const float*)d_in[2];   // [32,144,3,3]
    const float* bh    = (const float*)d_in[3];   // [32]
    const float* wsar  = (const float*)d_in[4];   // [32,4,3,3]
    const float* bs    = (const float*)d_in[5];   // [32]
    const float* W     = (const float*)d_in[6];   // [8192,10,16,8]
    float* out = (float*)d_out;                   // [64,10]

    char* ws = (char*)d_ws;
    short* wtb      = (short*)(ws + 0);           // 9*32*160*2   = 92160 B
    short* capsb    = (short*)(ws + 131072);      // [8192][64][8] bf16 = 8388608 B
    float* partials = (float*)(ws + 8519680);     // 128*10*64*16*4 = 5242880 B

    prep_w_kernel<<<180, 256, 0, stream>>>(wh, wtb);

    conv_both_kernel<<<576, 256, 0, stream>>>(x_hsi, wtb, bh, x_sar, wsar, bs, capsb);

    routing_mfma_kernel<<<dim3(128, 10), 256, 0, stream>>>(capsb, W, partials);

    finalize_kernel<<<64, 256, 0, stream>>>(partials, out);
}

// Round 5
// 140.703 us; speedup vs baseline: 1.0137x; 1.0137x over previous
//
#include <hip/hip_runtime.h>
#include <hip/hip_bf16.h>

// FastCapsNetMulti via bf16 MFMA, 4 launches:
//  k1 prep: blocks 0..179 wh->wtb[9][32][160] bf16; blocks 180..2227 x_hsi->xb[b][y][x][160] bf16
//  k2 conv_both: blocks 0..1023 HSI conv (global-read shifted MFMA GEMM),
//                blocks 1024..1087 SAR conv (fp32 VALU, uniform scalar weights)
//                both -> squash -> capsb[b][n][8] bf16 (coalesced writes)
//  k3 routing: s[b,cj] = sum caps*W; caps LDS-transposed per block, W fp32->bf16 inline
//  k4 finalize: reduce + squash + |v|
// B=64, H=W=32, N=8192, classes=10, class_dim=16, cap_dim=8.

typedef __attribute__((ext_vector_type(8))) short bf16x8s;
typedef __attribute__((ext_vector_type(4))) float f32x4;

__device__ inline short f2bf(float f) {
    __hip_bfloat16 h = __float2bfloat16(f);
    return *reinterpret_cast<short*>(&h);
}

// ---------------- k1: prep (weights + activations) ---------------------------
__global__ __launch_bounds__(256) void prep_kernel(
        const float* __restrict__ wh, short* __restrict__ wtb,
        const float* __restrict__ x_hsi, short* __restrict__ xb) {
    __shared__ short tile[160 * 33];
    int t = threadIdx.x;
    if (blockIdx.x < 180) {
        int idx = blockIdx.x * 256 + t;       // < 9*32*160 = 46080
        int tap = idx / 5120;
        int rest = idx - tap * 5120;
        int oc = rest / 160;
        int cin = rest - oc * 160;
        short v = 0;
        if (cin < 144) v = f2bf(wh[(oc * 144 + cin) * 9 + tap]);
        wtb[idx] = v;
        return;
    }
    int blk = blockIdx.x - 180;               // 0..2047 = (b, y)
    int b = blk >> 5;
    int y = blk & 31;
    for (int idx = t; idx < 512; idx += 256) {   // zero cin 144..159
        int x = idx & 31, cin = 144 + (idx >> 5);
        tile[cin * 33 + x] = 0;
    }
    for (int base = 0; base < 144; base += 8) {
        int cin = base + (t >> 5), x = t & 31;
        float v = x_hsi[(((size_t)b * 144 + cin) * 32 + y) * 32 + x];
        tile[cin * 33 + x] = f2bf(v);
    }
    __syncthreads();
    unsigned* dst = (unsigned*)(xb + ((size_t)(b * 32 + y) * 32) * 160);
    for (int idx = t; idx < 2560; idx += 256) {
        int x = idx / 80;
        int cinp = idx - x * 80;
        unsigned lo = (unsigned short)tile[(2 * cinp) * 33 + x];
        unsigned hi = (unsigned short)tile[(2 * cinp + 1) * 33 + x];
        dst[idx] = lo | (hi << 16);
    }
}

// ---------------- k2: fused conv (HSI MFMA + SAR VALU) -----------------------
// HSI: blocks 0..1023 = b(64) x ypair(16). 4 waves = (row mhalf) x (oc-tile nt).
// Wave C-tile: 32 px (one row, 2 x-halves) x 16 oc; K = 9 taps x 160 cin, A from
// global xb, B from global wtb (both L2-resident). C via LDS -> squash -> capsb.
// SAR: blocks 1024..1087 = b. Thread = 4 pixels, all 32 oc, uniform weights.
__global__ __launch_bounds__(256) void conv_both_kernel(
        const float* __restrict__ x_sar, const short* __restrict__ xb,
        const short* __restrict__ wtb, const float* __restrict__ bh,
        const float* __restrict__ wsar, const float* __restrict__ bs,
        short* __restrict__ capsb) {
    __shared__ float ctile[64][34];
    int t = threadIdx.x;

    if (blockIdx.x < 1024) {
        int l = t & 63;
        int wv = t >> 6;
        int mhalf = wv >> 1;
        int nt = wv & 1;
        int l15 = l & 15, lhi = l >> 4;
        int b = blockIdx.x >> 4;
        int y0 = (blockIdx.x & 15) << 1;
        int y = y0 + mhalf;
        int kofs = lhi * 8;

        const short* xbb = xb + (size_t)b * 1024 * 160;

        f32x4 acc0 = {0.f, 0.f, 0.f, 0.f};
        f32x4 acc1 = {0.f, 0.f, 0.f, 0.f};
        const bf16x8s zf = {0, 0, 0, 0, 0, 0, 0, 0};

        #pragma unroll
        for (int tap = 0; tap < 9; ++tap) {
            int dy = tap / 3, dx = tap % 3;
            int iy = y + dy - 1;
            bool rowok = (unsigned)iy < 32u;
            int iyc = rowok ? iy : 0;
            int ix0 = l15 + dx - 1;
            int ix1 = 16 + l15 + dx - 1;
            bool ok0 = rowok && ((unsigned)ix0 < 32u);
            bool ok1 = rowok && ((unsigned)ix1 < 32u);
            int ix0c = min(max(ix0, 0), 31);
            int ix1c = min(max(ix1, 0), 31);
            const short* xa0 = xbb + ((size_t)(iyc * 32 + ix0c)) * 160 + kofs;
            const short* xa1 = xbb + ((size_t)(iyc * 32 + ix1c)) * 160 + kofs;
            const short* wa = wtb + ((size_t)tap * 32 + nt * 16 + l15) * 160 + kofs;
            #pragma unroll
            for (int kc = 0; kc < 5; ++kc) {
                bf16x8s bfrag = *(const bf16x8s*)(wa + kc * 32);
                bf16x8s a0 = *(const bf16x8s*)(xa0 + kc * 32);
                bf16x8s a1 = *(const bf16x8s*)(xa1 + kc * 32);
                a0 = ok0 ? a0 : zf;
                a1 = ok1 ? a1 : zf;
                acc0 = __builtin_amdgcn_mfma_f32_16x16x32_bf16(a0, bfrag, acc0, 0, 0, 0);
                acc1 = __builtin_amdgcn_mfma_f32_16x16x32_bf16(a1, bfrag, acc1, 0, 0, 0);
            }
        }

        #pragma unroll
        for (int r = 0; r < 4; ++r) {
            ctile[mhalf * 32 + lhi * 4 + r][nt * 16 + l15] = acc0[r];
            ctile[mhalf * 32 + 16 + lhi * 4 + r][nt * 16 + l15] = acc1[r];
        }
        __syncthreads();

        int p = t >> 2;          // local pixel 0..63
        int cap = t & 3;
        float s[8];
        float sq = 0.0f;
        #pragma unroll
        for (int d = 0; d < 8; ++d) {
            s[d] = ctile[p][cap * 8 + d] + bh[cap * 8 + d];
            sq += s[d] * s[d];
        }
        float scale = sq / ((1.0f + sq) * sqrtf(sq + 1e-8f));
        int pix = (y0 + (p >> 5)) * 32 + (p & 31);
        int n = pix * 4 + cap;
        bf16x8s o;
        #pragma unroll
        for (int d = 0; d < 8; ++d) o[d] = f2bf(s[d] * scale);
        *(bf16x8s*)(capsb + ((size_t)b * 8192 + n) * 8) = o;
    } else {
        int b = blockIdx.x - 1024;
        const float* xb_ = x_sar + (size_t)b * 4 * 1024;
        for (int i = 0; i < 4; ++i) {
            int px = t + i * 256;
            int y = px >> 5, x = px & 31;
            float acc[32];
            #pragma unroll
            for (int oc = 0; oc < 32; ++oc) acc[oc] = bs[oc];
            #pragma unroll
            for (int tap = 0; tap < 9; ++tap) {
                int dy = tap / 3, dx = tap % 3;
                int iy = y + dy - 1, ix = x + dx - 1;
                bool ok = ((unsigned)iy < 32u) && ((unsigned)ix < 32u);
                int off = ok ? (iy * 32 + ix) : 0;
                float v[4];
                #pragma unroll
                for (int ch = 0; ch < 4; ++ch) {
                    float ld = xb_[(size_t)ch * 1024 + off];
                    v[ch] = ok ? ld : 0.0f;
                }
                #pragma unroll
                for (int oc = 0; oc < 32; ++oc)
                    #pragma unroll
                    for (int ch = 0; ch < 4; ++ch)
                        acc[oc] += v[ch] * wsar[(oc * 4 + ch) * 9 + tap];
            }
            #pragma unroll
            for (int cap = 0; cap < 4; ++cap) {
                float sq = 0.0f;
                #pragma unroll
                for (int d = 0; d < 8; ++d) sq += acc[cap * 8 + d] * acc[cap * 8 + d];
                float scale = sq / ((1.0f + sq) * sqrtf(sq + 1e-8f));
                int n = 4096 + px * 4 + cap;
                bf16x8s o;
                #pragma unroll
                for (int d = 0; d < 8; ++d) o[d] = f2bf(acc[cap * 8 + d] * scale);
                *(bf16x8s*)(capsb + ((size_t)b * 8192 + n) * 8) = o;
            }
        }
    }
}

// ---------------- k3: routing via MFMA ---------------------------------------
// grid (kc 128) x (ntp 5). Block: stage caps[b][kc*64 .. +64] -> LDS [n][b][8]
// (transpose on write), then 16 K-steps (4 per wave), 2 cj-tiles per block.
__global__ __launch_bounds__(256) void routing_mfma_kernel(
        const short* __restrict__ capsb, const float* __restrict__ W,
        float* __restrict__ partials) {
    __shared__ union {
        short ct[64][64][8];    // [n_local][b][8] = 65536 B
        float red[4][64][34];   // cross-wave reduce (34-pad)
    } sm;
    int t = threadIdx.x;
    int kc = blockIdx.x;
    int ntp = blockIdx.y;
    int n0 = kc * 64;

    {   // stage: thread t: b = t>>2, ng = t&3; 16x contiguous 16B global reads
        int b = t >> 2;
        int ng = t & 3;
        const short* src = capsb + ((size_t)b * 8192 + n0 + ng * 16) * 8;
        #pragma unroll
        for (int i = 0; i < 16; ++i) {
            bf16x8s v = *(const bf16x8s*)(src + i * 8);
            *(bf16x8s*)&sm.ct[ng * 16 + i][b][0] = v;
        }
    }
    __syncthreads();

    int l = t & 63;
    int wv = t >> 6;
    int l15 = l & 15, lhi = l >> 4;

    f32x4 acc[2][4];
    #pragma unroll
    for (int a = 0; a < 2; ++a)
        #pragma unroll
        for (int m = 0; m < 4; ++m) acc[a][m] = (f32x4){0.f, 0.f, 0.f, 0.f};

    #pragma unroll
    for (int ks = 0; ks < 4; ++ks) {
        int nl = (wv * 4 + ks) * 4 + lhi;     // n_local 0..63
        int n = n0 + nl;
        const float* wp = W + ((size_t)n * 160 + ntp * 32 + l15) * 8;
        union { short s[8]; bf16x8s v; } bu[2];
        #pragma unroll
        for (int ntl = 0; ntl < 2; ++ntl) {
            const float* wq = wp + (size_t)ntl * 128;   // +16 cj
            float4 w0 = *(const float4*)wq;
            float4 w1 = *(const float4*)(wq + 4);
            bu[ntl].s[0] = f2bf(w0.x); bu[ntl].s[1] = f2bf(w0.y);
            bu[ntl].s[2] = f2bf(w0.z); bu[ntl].s[3] = f2bf(w0.w);
            bu[ntl].s[4] = f2bf(w1.x); bu[ntl].s[5] = f2bf(w1.y);
            bu[ntl].s[6] = f2bf(w1.z); bu[ntl].s[7] = f2bf(w1.w);
        }
        bf16x8s af[4];
        #pragma unroll
        for (int mt = 0; mt < 4; ++mt)
            af[mt] = *(const bf16x8s*)&sm.ct[nl][mt * 16 + l15][0];
        #pragma unroll
        for (int ntl = 0; ntl < 2; ++ntl)
            #pragma unroll
            for (int mt = 0; mt < 4; ++mt)
                acc[ntl][mt] = __builtin_amdgcn_mfma_f32_16x16x32_bf16(
                    af[mt], bu[ntl].v, acc[ntl][mt], 0, 0, 0);
    }
    __syncthreads();   // all ct reads done before red overwrites

    #pragma unroll
    for (int ntl = 0; ntl < 2; ++ntl)
        #pragma unroll
        for (int mt = 0; mt < 4; ++mt)
            #pragma unroll
            for (int r = 0; r < 4; ++r)
                sm.red[wv][mt * 16 + lhi * 4 + r][ntl * 16 + l15] = acc[ntl][mt][r];
    __syncthreads();

    for (int idx = t; idx < 2048; idx += 256) {
        int b = idx >> 5, cjl = idx & 31;
        float sum = sm.red[0][b][cjl] + sm.red[1][b][cjl]
                  + sm.red[2][b][cjl] + sm.red[3][b][cjl];
        partials[(((size_t)kc * 5 + ntp) * 64 + b) * 32 + cjl] = sum;
    }
}

// ---------------- k4: final reduce + squash + norm ---------------------------
__global__ __launch_bounds__(256) void finalize_kernel(
        const float* __restrict__ partials, float* __restrict__ out) {
    __shared__ float s_sh[160];
    int t = threadIdx.x;
    int b = blockIdx.x;
    if (t < 160) {
        int ntp = t >> 5, cjl = t & 31;
        float s = 0.0f;
        #pragma unroll 8
        for (int kc = 0; kc < 128; ++kc)
            s += partials[(((size_t)kc * 5 + ntp) * 64 + b) * 32 + cjl];
        s_sh[ntp * 32 + cjl] = s * (1.0f / 8192.0f);
    }
    __syncthreads();
    if (t < 10) {
        float sq = 0.0f;
        #pragma unroll
        for (int j = 0; j < 16; ++j) {
            float v = s_sh[t * 16 + j];
            sq += v * v;
        }
        float scale = sq / ((1.0f + sq) * sqrtf(sq + 1e-8f));
        out[b * 10 + t] = sqrtf(sq) * scale;
    }
}

extern "C" void kernel_launch(void* const* d_in, const int* in_sizes, int n_in,
                              void* d_out, int out_size, void* d_ws, size_t ws_size,
                              hipStream_t stream) {
    const float* x_hsi = (const float*)d_in[0];   // [64,144,32,32]
    const float* x_sar = (const float*)d_in[1];   // [64,4,32,32]
    const float* wh    = (const float*)d_in[2];   // [32,144,3,3]
    const float* bh    = (const float*)d_in[3];   // [32]
    const float* wsar  = (const float*)d_in[4];   // [32,4,3,3]
    const float* bs    = (const float*)d_in[5];   // [32]
    const float* W     = (const float*)d_in[6];   // [8192,10,16,8]
    float* out = (float*)d_out;                   // [64,10]

    char* ws = (char*)d_ws;
    short* wtb      = (short*)(ws + 0);           // 9*32*160*2 = 92160 B
    short* xb       = (short*)(ws + 131072);      // [64][32][32][160] bf16 = 20971520 B
    short* capsb    = (short*)(ws + 21102592);    // [64][8192][8] bf16 = 8388608 B
    float* partials = (float*)(ws + 29491200);    // 128*5*64*32*4 = 5242880 B

    prep_kernel<<<2228, 256, 0, stream>>>(wh, wtb, x_hsi, xb);

    conv_both_kernel<<<1088, 256, 0, stream>>>(x_sar, xb, wtb, bh, wsar, bs, capsb);

    routing_mfma_kernel<<<dim3(128, 5), 256, 0, stream>>>(capsb, W, partials);

    finalize_kernel<<<64, 256, 0, stream>>>(partials, out);
}

// Round 6
// 76.434 us; speedup vs baseline: 1.8660x; 1.8409x over previous
//
#include <hip/hip_runtime.h>
#include <hip/hip_bf16.h>

// FastCapsNetMulti via bf16 MFMA, 4 launches:
//  k1 prep: blocks 0..179 wh->wtb[9][32][160] bf16; blocks 180..2227 x_hsi->xb;
//           block 2228 wsar->wt_s[cin][tap][oc] fp32 (oc-contiguous for s_load_dwordx)
//  k2 conv_both: blocks 0..1023 HSI conv (global-read shifted MFMA GEMM)
//                blocks 1024..2047 SAR conv (fp32 VALU, wave-uniform cin, LDS reduce)
//                both -> squash -> capsb[b][n][8] bf16 (coalesced writes)
//  k3 routing: s[b,cj] = sum caps*W; caps LDS-transposed per block, W fp32->bf16 inline
//  k4 finalize: reduce + squash + |v|
// B=64, H=W=32, N=8192, classes=10, class_dim=16, cap_dim=8.

typedef __attribute__((ext_vector_type(8))) short bf16x8s;
typedef __attribute__((ext_vector_type(4))) float f32x4;

__device__ inline short f2bf(float f) {
    __hip_bfloat16 h = __float2bfloat16(f);
    return *reinterpret_cast<short*>(&h);
}

// ---------------- k1: prep (weights + activations) ---------------------------
__global__ __launch_bounds__(256) void prep_kernel(
        const float* __restrict__ wh, short* __restrict__ wtb,
        const float* __restrict__ x_hsi, short* __restrict__ xb,
        const float* __restrict__ wsar, float* __restrict__ wt_s) {
    __shared__ short tile[160 * 33];
    int t = threadIdx.x;
    if (blockIdx.x < 180) {
        int idx = blockIdx.x * 256 + t;       // < 9*32*160 = 46080
        int tap = idx / 5120;
        int rest = idx - tap * 5120;
        int oc = rest / 160;
        int cin = rest - oc * 160;
        short v = 0;
        if (cin < 144) v = f2bf(wh[(oc * 144 + cin) * 9 + tap]);
        wtb[idx] = v;
        return;
    }
    if (blockIdx.x == 2228) {                 // SAR weight transpose
        for (int idx = t; idx < 1152; idx += 256) {
            int oc = idx & 31;
            int rest = idx >> 5;
            int tap = rest % 9;
            int cin = rest / 9;
            wt_s[cin * 288 + tap * 32 + oc] = wsar[(oc * 4 + cin) * 9 + tap];
        }
        return;
    }
    int blk = blockIdx.x - 180;               // 0..2047 = (b, y)
    int b = blk >> 5;
    int y = blk & 31;
    for (int idx = t; idx < 512; idx += 256) {   // zero cin 144..159
        int x = idx & 31, cin = 144 + (idx >> 5);
        tile[cin * 33 + x] = 0;
    }
    for (int base = 0; base < 144; base += 8) {
        int cin = base + (t >> 5), x = t & 31;
        float v = x_hsi[(((size_t)b * 144 + cin) * 32 + y) * 32 + x];
        tile[cin * 33 + x] = f2bf(v);
    }
    __syncthreads();
    unsigned* dst = (unsigned*)(xb + ((size_t)(b * 32 + y) * 32) * 160);
    for (int idx = t; idx < 2560; idx += 256) {
        int x = idx / 80;
        int cinp = idx - x * 80;
        unsigned lo = (unsigned short)tile[(2 * cinp) * 33 + x];
        unsigned hi = (unsigned short)tile[(2 * cinp + 1) * 33 + x];
        dst[idx] = lo | (hi << 16);
    }
}

// ---------------- k2: fused conv (HSI MFMA + SAR VALU) -----------------------
// HSI: blocks 0..1023 = b(64) x ypair(16). 4 waves = (row mhalf) x (oc-tile nt).
// Wave C-tile: 32 px (one row, 2 x-halves) x 16 oc; K = 9 taps x 160 cin, A/B
// from global (L2/L3-resident). C via LDS -> squash -> capsb.
// SAR: blocks 1024..2047 = b(64) x ypair(16). Wave = cin (uniform weights,
// oc-contiguous -> s_load_dwordx), LDS cross-wave reduce.
__global__ __launch_bounds__(256) void conv_both_kernel(
        const float* __restrict__ x_sar, const short* __restrict__ xb,
        const short* __restrict__ wtb, const float* __restrict__ bh,
        const float* __restrict__ wt_s, const float* __restrict__ bs,
        short* __restrict__ capsb) {
    __shared__ union {
        float ct[64][34];       // HSI C-tile (8704 B)
        float red[4][32][64];   // SAR cross-wave reduce (32768 B)
    } sm;
    int t = threadIdx.x;

    if (blockIdx.x < 1024) {
        int l = t & 63;
        int wv = t >> 6;
        int mhalf = wv >> 1;
        int nt = wv & 1;
        int l15 = l & 15, lhi = l >> 4;
        int b = blockIdx.x >> 4;
        int y0 = (blockIdx.x & 15) << 1;
        int y = y0 + mhalf;
        int kofs = lhi * 8;

        const short* xbb = xb + (size_t)b * 1024 * 160;

        f32x4 acc0 = {0.f, 0.f, 0.f, 0.f};
        f32x4 acc1 = {0.f, 0.f, 0.f, 0.f};
        const bf16x8s zf = {0, 0, 0, 0, 0, 0, 0, 0};

        #pragma unroll
        for (int tap = 0; tap < 9; ++tap) {
            int dy = tap / 3, dx = tap % 3;
            int iy = y + dy - 1;
            bool rowok = (unsigned)iy < 32u;
            int iyc = rowok ? iy : 0;
            int ix0 = l15 + dx - 1;
            int ix1 = 16 + l15 + dx - 1;
            bool ok0 = rowok && ((unsigned)ix0 < 32u);
            bool ok1 = rowok && ((unsigned)ix1 < 32u);
            int ix0c = min(max(ix0, 0), 31);
            int ix1c = min(max(ix1, 0), 31);
            const short* xa0 = xbb + ((size_t)(iyc * 32 + ix0c)) * 160 + kofs;
            const short* xa1 = xbb + ((size_t)(iyc * 32 + ix1c)) * 160 + kofs;
            const short* wa = wtb + ((size_t)tap * 32 + nt * 16 + l15) * 160 + kofs;
            #pragma unroll
            for (int kc = 0; kc < 5; ++kc) {
                bf16x8s bfrag = *(const bf16x8s*)(wa + kc * 32);
                bf16x8s a0 = *(const bf16x8s*)(xa0 + kc * 32);
                bf16x8s a1 = *(const bf16x8s*)(xa1 + kc * 32);
                a0 = ok0 ? a0 : zf;
                a1 = ok1 ? a1 : zf;
                acc0 = __builtin_amdgcn_mfma_f32_16x16x32_bf16(a0, bfrag, acc0, 0, 0, 0);
                acc1 = __builtin_amdgcn_mfma_f32_16x16x32_bf16(a1, bfrag, acc1, 0, 0, 0);
            }
        }

        #pragma unroll
        for (int r = 0; r < 4; ++r) {
            sm.ct[mhalf * 32 + lhi * 4 + r][nt * 16 + l15] = acc0[r];
            sm.ct[mhalf * 32 + 16 + lhi * 4 + r][nt * 16 + l15] = acc1[r];
        }
        __syncthreads();

        int p = t >> 2;          // local pixel 0..63
        int cap = t & 3;
        float s[8];
        float sq = 0.0f;
        #pragma unroll
        for (int d = 0; d < 8; ++d) {
            s[d] = sm.ct[p][cap * 8 + d] + bh[cap * 8 + d];
            sq += s[d] * s[d];
        }
        float scale = sq / ((1.0f + sq) * sqrtf(sq + 1e-8f));
        int pix = (y0 + (p >> 5)) * 32 + (p & 31);
        int n = pix * 4 + cap;
        bf16x8s o;
        #pragma unroll
        for (int d = 0; d < 8; ++d) o[d] = f2bf(s[d] * scale);
        *(bf16x8s*)(capsb + ((size_t)b * 8192 + n) * 8) = o;
    } else {
        // ---- SAR: wave-uniform cin, oc-contiguous scalar weights ------------
        int bidx = blockIdx.x - 1024;      // 0..1023
        int b = bidx >> 4;
        int wave = __builtin_amdgcn_readfirstlane(t >> 6);
        int lane = t & 63;
        int x = lane & 31;
        int yy = lane >> 5;
        int y = ((bidx & 15) << 1) + yy;

        const float* xc = x_sar + ((size_t)b * 4 + wave) * 1024;
        const float* wc = wt_s + wave * 288;

        float acc[32];
        #pragma unroll
        for (int oc = 0; oc < 32; ++oc) acc[oc] = 0.0f;

        #pragma unroll
        for (int ky = 0; ky < 3; ++ky) {
            int iy = y + ky - 1;
            bool rowok = (iy >= 0) && (iy < 32);
            const float* xrow = xc + iy * 32;
            float v0 = (rowok && x > 0)  ? xrow[x - 1] : 0.0f;
            float v1 = rowok             ? xrow[x]     : 0.0f;
            float v2 = (rowok && x < 31) ? xrow[x + 1] : 0.0f;
            const float* wk = wc + ky * 96;
            #pragma unroll
            for (int oc = 0; oc < 32; ++oc)
                acc[oc] += v0 * wk[oc] + v1 * wk[32 + oc] + v2 * wk[64 + oc];
        }

        #pragma unroll
        for (int oc = 0; oc < 32; ++oc) sm.red[wave][oc][lane] = acc[oc];
        __syncthreads();

        int cap = t >> 6;
        int p = t & 63;
        float s[8];
        float sq = 0.0f;
        #pragma unroll
        for (int d = 0; d < 8; ++d) {
            int oc = cap * 8 + d;
            s[d] = bs[oc] + sm.red[0][oc][p] + sm.red[1][oc][p]
                          + sm.red[2][oc][p] + sm.red[3][oc][p];
            sq += s[d] * s[d];
        }
        float scale = sq / ((1.0f + sq) * sqrtf(sq + 1e-8f));
        int pix = (((bidx & 15) << 1) + (p >> 5)) * 32 + (p & 31);
        int n = 4096 + pix * 4 + cap;
        bf16x8s o;
        #pragma unroll
        for (int d = 0; d < 8; ++d) o[d] = f2bf(s[d] * scale);
        *(bf16x8s*)(capsb + ((size_t)b * 8192 + n) * 8) = o;
    }
}

// ---------------- k3: routing via MFMA ---------------------------------------
// grid (kc 128) x (ntp 5). Block: stage caps[b][kc*64 .. +64] -> LDS [n][b][8]
// (transpose on write), then 16 K-steps (4 per wave), 2 cj-tiles per block.
__global__ __launch_bounds__(256) void routing_mfma_kernel(
        const short* __restrict__ capsb, const float* __restrict__ W,
        float* __restrict__ partials) {
    __shared__ union {
        short ct[64][64][8];    // [n_local][b][8] = 65536 B
        float red[4][64][34];   // cross-wave reduce (34-pad)
    } sm;
    int t = threadIdx.x;
    int kc = blockIdx.x;
    int ntp = blockIdx.y;
    int n0 = kc * 64;

    {   // stage: thread t: b = t>>2, ng = t&3; 16x contiguous 16B global reads
        int b = t >> 2;
        int ng = t & 3;
        const short* src = capsb + ((size_t)b * 8192 + n0 + ng * 16) * 8;
        #pragma unroll
        for (int i = 0; i < 16; ++i) {
            bf16x8s v = *(const bf16x8s*)(src + i * 8);
            *(bf16x8s*)&sm.ct[ng * 16 + i][b][0] = v;
        }
    }
    __syncthreads();

    int l = t & 63;
    int wv = t >> 6;
    int l15 = l & 15, lhi = l >> 4;

    f32x4 acc[2][4];
    #pragma unroll
    for (int a = 0; a < 2; ++a)
        #pragma unroll
        for (int m = 0; m < 4; ++m) acc[a][m] = (f32x4){0.f, 0.f, 0.f, 0.f};

    #pragma unroll
    for (int ks = 0; ks < 4; ++ks) {
        int nl = (wv * 4 + ks) * 4 + lhi;     // n_local 0..63
        int n = n0 + nl;
        const float* wp = W + ((size_t)n * 160 + ntp * 32 + l15) * 8;
        union { short s[8]; bf16x8s v; } bu[2];
        #pragma unroll
        for (int ntl = 0; ntl < 2; ++ntl) {
            const float* wq = wp + (size_t)ntl * 128;   // +16 cj
            float4 w0 = *(const float4*)wq;
            float4 w1 = *(const float4*)(wq + 4);
            bu[ntl].s[0] = f2bf(w0.x); bu[ntl].s[1] = f2bf(w0.y);
            bu[ntl].s[2] = f2bf(w0.z); bu[ntl].s[3] = f2bf(w0.w);
            bu[ntl].s[4] = f2bf(w1.x); bu[ntl].s[5] = f2bf(w1.y);
            bu[ntl].s[6] = f2bf(w1.z); bu[ntl].s[7] = f2bf(w1.w);
        }
        bf16x8s af[4];
        #pragma unroll
        for (int mt = 0; mt < 4; ++mt)
            af[mt] = *(const bf16x8s*)&sm.ct[nl][mt * 16 + l15][0];
        #pragma unroll
        for (int ntl = 0; ntl < 2; ++ntl)
            #pragma unroll
            for (int mt = 0; mt < 4; ++mt)
                acc[ntl][mt] = __builtin_amdgcn_mfma_f32_16x16x32_bf16(
                    af[mt], bu[ntl].v, acc[ntl][mt], 0, 0, 0);
    }
    __syncthreads();   // all ct reads done before red overwrites

    #pragma unroll
    for (int ntl = 0; ntl < 2; ++ntl)
        #pragma unroll
        for (int mt = 0; mt < 4; ++mt)
            #pragma unroll
            for (int r = 0; r < 4; ++r)
                sm.red[wv][mt * 16 + lhi * 4 + r][ntl * 16 + l15] = acc[ntl][mt][r];
    __syncthreads();

    for (int idx = t; idx < 2048; idx += 256) {
        int b = idx >> 5, cjl = idx & 31;
        float sum = sm.red[0][b][cjl] + sm.red[1][b][cjl]
                  + sm.red[2][b][cjl] + sm.red[3][b][cjl];
        partials[(((size_t)kc * 5 + ntp) * 64 + b) * 32 + cjl] = sum;
    }
}

// ---------------- k4: final reduce + squash + norm ---------------------------
__global__ __launch_bounds__(256) void finalize_kernel(
        const float* __restrict__ partials, float* __restrict__ out) {
    __shared__ float s_sh[160];
    int t = threadIdx.x;
    int b = blockIdx.x;
    if (t < 160) {
        int ntp = t >> 5, cjl = t & 31;
        float s = 0.0f;
        #pragma unroll 8
        for (int kc = 0; kc < 128; ++kc)
            s += partials[(((size_t)kc * 5 + ntp) * 64 + b) * 32 + cjl];
        s_sh[ntp * 32 + cjl] = s * (1.0f / 8192.0f);
    }
    __syncthreads();
    if (t < 10) {
        float sq = 0.0f;
        #pragma unroll
        for (int j = 0; j < 16; ++j) {
            float v = s_sh[t * 16 + j];
            sq += v * v;
        }
        float scale = sq / ((1.0f + sq) * sqrtf(sq + 1e-8f));
        out[b * 10 + t] = sqrtf(sq) * scale;
    }
}

extern "C" void kernel_launch(void* const* d_in, const int* in_sizes, int n_in,
                              void* d_out, int out_size, void* d_ws, size_t ws_size,
                              hipStream_t stream) {
    const float* x_hsi = (const float*)d_in[0];   // [64,144,32,32]
    const float* x_sar = (const float*)d_in[1];   // [64,4,32,32]
    const float* wh    = (const float*)d_in[2];   // [32,144,3,3]
    const float* bh    = (const float*)d_in[3];   // [32]
    const float* wsar  = (const float*)d_in[4];   // [32,4,3,3]
    const float* bs    = (const float*)d_in[5];   // [32]
    const float* W     = (const float*)d_in[6];   // [8192,10,16,8]
    float* out = (float*)d_out;                   // [64,10]

    char* ws = (char*)d_ws;
    short* wtb      = (short*)(ws + 0);           // 9*32*160*2 = 92160 B
    float* wt_s     = (float*)(ws + 98304);       // 4*9*32*4 = 4608 B
    short* xb       = (short*)(ws + 131072);      // [64][32][32][160] bf16 = 20971520 B
    short* capsb    = (short*)(ws + 21102592);    // [64][8192][8] bf16 = 8388608 B
    float* partials = (float*)(ws + 29491200);    // 128*5*64*32*4 = 5242880 B

    prep_kernel<<<2229, 256, 0, stream>>>(wh, wtb, x_hsi, xb, wsar, wt_s);

    conv_both_kernel<<<2048, 256, 0, stream>>>(x_sar, xb, wtb, bh, wt_s, bs, capsb);

    routing_mfma_kernel<<<dim3(128, 5), 256, 0, stream>>>(capsb, W, partials);

    finalize_kernel<<<64, 256, 0, stream>>>(partials, out);
}